// Round 4
// baseline (252.476 us; speedup 1.0000x reference)
//
#include <hip/hip_runtime.h>

#define NF 64
#define ND 32
#define NPAIR 2016

typedef __attribute__((ext_vector_type(8))) short bf16x8;
typedef __attribute__((ext_vector_type(4))) float f32x4;

// 256 threads = 4 waves, one sample per wave. No LDS at all: MFMA fragments
// are loaded directly from global (the Gram A/B fragment layout is a
// contiguous coalesced pattern), split fp32 -> bf16 hi+lo in registers.
__global__ __launch_bounds__(256, 4) void ip_gram_mfma(
    const float* __restrict__ in, float* __restrict__ out) {

    const int t = threadIdx.x;
    const int w = t >> 6;
    const int l = t & 63;
    const int s = blockIdx.x * 4 + w;

    const float* src = in + (size_t)s * (NF * ND);
    const int q = l >> 4;          // k-quad: covers dims q*8..q*8+7
    const int m = l & 15;          // field within 16-row block

    // ---- direct fragment loads + fp32 -> bf16 hi/lo split ----
    bf16x8 fhi[4], flo[4];
    #pragma unroll
    for (int r = 0; r < 4; ++r) {
        const float* p = src + (r * 16 + m) * ND + (q << 3);  // 32B-aligned
        float4 u0 = *(const float4*)p;
        float4 u1 = *(const float4*)(p + 4);
        float xv[8] = {u0.x, u0.y, u0.z, u0.w, u1.x, u1.y, u1.z, u1.w};
        #pragma unroll
        for (int e = 0; e < 8; ++e) {
            unsigned xb = __builtin_bit_cast(unsigned, xv[e]);
            fhi[r][e] = (short)(xb >> 16);                          // truncate -> hi
            float hf = __builtin_bit_cast(float, xb & 0xFFFF0000u);
            float lf = xv[e] - hf;                                  // exact residual
            flo[r][e] = (short)(__builtin_bit_cast(unsigned, lf) >> 16);
        }
    }

    // ---- upper tiles: D = Xhi*Xhi^T + Xhi*Xlo^T + Xlo*Xhi^T ----
    float* dst = out + (size_t)s * NPAIR;
    #pragma unroll
    for (int ti = 0; ti < 4; ++ti) {
        #pragma unroll
        for (int tj = ti; tj < 4; ++tj) {
            f32x4 c = {0.f, 0.f, 0.f, 0.f};
            c = __builtin_amdgcn_mfma_f32_16x16x32_bf16(fhi[ti], fhi[tj], c, 0, 0, 0);
            c = __builtin_amdgcn_mfma_f32_16x16x32_bf16(fhi[ti], flo[tj], c, 0, 0, 0);
            c = __builtin_amdgcn_mfma_f32_16x16x32_bf16(flo[ti], fhi[tj], c, 0, 0, 0);
            // C/D layout: i = ti*16 + q*4 + reg, j = tj*16 + m
            int j = tj * 16 + m;
            #pragma unroll
            for (int r = 0; r < 4; ++r) {
                int i = ti * 16 + (q << 2) + r;
                if (ti < tj || j > i) {
                    int p = ((i * (127 - i)) >> 1) + j - i - 1;
                    dst[p] = c[r];   // quarter-wave 64B contiguous segments
                }
            }
        }
    }
}

extern "C" void kernel_launch(void* const* d_in, const int* in_sizes, int n_in,
                              void* d_out, int out_size, void* d_ws, size_t ws_size,
                              hipStream_t stream) {
    const float* in = (const float*)d_in[0];
    float* out = (float*)d_out;
    const int nsamples = in_sizes[0] / (NF * ND);   // 16384
    ip_gram_mfma<<<nsamples / 4, 256, 0, stream>>>(in, out);
}

// Round 5
// 243.387 us; speedup vs baseline: 1.0373x; 1.0373x over previous
//
#include <hip/hip_runtime.h>

#define NF 64
#define ND 32
#define NPAIR 2016
#define WPB 4      // waves per block
#define SPW 4      // samples per wave (pipelined)

typedef __attribute__((ext_vector_type(8))) short bf16x8;
typedef __attribute__((ext_vector_type(4))) float f32x4;

// 256 threads = 4 waves. Each wave processes 4 samples, software-pipelined:
// next sample's fragment loads are issued before the current sample's
// MFMA+epilogue. Epilogue repacks the triangle through wave-private LDS so
// all global stores are coalesced dwordx4. No __syncthreads anywhere.
__global__ __launch_bounds__(256, 4) void ip_gram_mfma(
    const float* __restrict__ in, float* __restrict__ out) {

    __shared__ float gbuf[WPB][2048];          // 32 KiB: per-wave repack buffer

    const int t = threadIdx.x;
    const int w = t >> 6;
    const int l = t & 63;
    const int q = l >> 4;                      // k-quad (dims q*8..q*8+7)
    const int m = l & 15;                      // field within 16-block

    float* g = gbuf[w];
    const int sbase = blockIdx.x * (WPB * SPW) + w;   // iteration it: s = sbase + it*WPB

    float4 raw[8];                             // raw fp32 fragment staging

    // issue the 8 coalesced fragment loads for sample s
    auto issue_loads = [&](int s) {
        const float* src = in + (size_t)s * (NF * ND);
        #pragma unroll
        for (int r = 0; r < 4; ++r) {
            const float* p = src + (r * 16 + m) * ND + (q << 3);   // 32B/lane
            raw[2 * r]     = *(const float4*)p;
            raw[2 * r + 1] = *(const float4*)(p + 4);
        }
    };

    issue_loads(sbase);

    #pragma unroll
    for (int it = 0; it < SPW; ++it) {
        // ---- convert current raw -> bf16 hi/lo fragments ----
        bf16x8 fhi[4], flo[4];
        #pragma unroll
        for (int r = 0; r < 4; ++r) {
            float xv[8];
            *(float4*)&xv[0] = raw[2 * r];
            *(float4*)&xv[4] = raw[2 * r + 1];
            #pragma unroll
            for (int e = 0; e < 8; ++e) {
                unsigned xb = __builtin_bit_cast(unsigned, xv[e]);
                fhi[r][e] = (short)(xb >> 16);                         // truncate hi
                float hf = __builtin_bit_cast(float, xb & 0xFFFF0000u);
                float lf = xv[e] - hf;                                 // exact residual
                flo[r][e] = (short)(__builtin_bit_cast(unsigned, lf) >> 16);
            }
        }

        // ---- prefetch next sample (overlaps MFMA + epilogue below) ----
        if (it + 1 < SPW) issue_loads(sbase + (it + 1) * WPB);

        // ---- MFMA upper tiles, scatter into flat-packed LDS triangle ----
        #pragma unroll
        for (int ti = 0; ti < 4; ++ti) {
            #pragma unroll
            for (int tj = ti; tj < 4; ++tj) {
                f32x4 c = {0.f, 0.f, 0.f, 0.f};
                c = __builtin_amdgcn_mfma_f32_16x16x32_bf16(fhi[ti], fhi[tj], c, 0, 0, 0);
                c = __builtin_amdgcn_mfma_f32_16x16x32_bf16(fhi[ti], flo[tj], c, 0, 0, 0);
                c = __builtin_amdgcn_mfma_f32_16x16x32_bf16(flo[ti], fhi[tj], c, 0, 0, 0);
                int j = tj * 16 + m;           // C/D: i = ti*16 + q*4 + r, j = tj*16 + m
                #pragma unroll
                for (int r = 0; r < 4; ++r) {
                    int i = ti * 16 + (q << 2) + r;
                    if (ti < tj || j > i) {
                        int p = ((i * (127 - i)) >> 1) + j - i - 1;
                        g[p] = c[r];
                    }
                }
            }
        }

        // ---- coalesced stream-out: 504 float4 ----
        float* dst = out + (size_t)(sbase + it * WPB) * NPAIR;
        #pragma unroll
        for (int k = 0; k < 8; ++k) {
            int idx4 = (k << 6) + l;
            if (idx4 < 504) {
                float4 v = *(const float4*)(g + (idx4 << 2));
                *(float4*)(dst + (idx4 << 2)) = v;
            }
        }
    }
}

extern "C" void kernel_launch(void* const* d_in, const int* in_sizes, int n_in,
                              void* d_out, int out_size, void* d_ws, size_t ws_size,
                              hipStream_t stream) {
    const float* in = (const float*)d_in[0];
    float* out = (float*)d_out;
    const int nsamples = in_sizes[0] / (NF * ND);          // 16384
    ip_gram_mfma<<<nsamples / (WPB * SPW), 256, 0, stream>>>(in, out);
}